// Round 4
// baseline (1830.962 us; speedup 1.0000x reference)
//
#include <hip/hip_runtime.h>

// GRU decoder, bf16 MFMA. R11 = R10 resubmitted (R10 bench was an infra
// failure: "container failed twice", no profile; kernel audited clean --
// uniform barriers, LDS 59.5KB, all accesses in-bounds).
//
// R10 rationale: fit the 64-arch-VGPR budget, end the spills.
// R9 post-mortem: 16-wave block => 4 waves/SIMD => hard 128-reg unified cap,
// compiler split 64 arch + 64 acc. Forced ~73 live arch regs (explicit
// distance-1 frag dbuf + prevreg array) => per-step scratch spills (152 MB
// HBM writebacks) which thrash the 480 KB weight set out of L2 (4.29 GB
// fetch, ~36% weight-stream HBM miss @ ~900cy) => MfmaUtil stuck at 10.9%.
// Changes vs R9:
//  * single-buffered weight frags, no explicit prefetch: at 4 waves/SIMD,
//    TLP hides the ~200cy L2 hit; the ILP pipeline was only needed at 2
//    waves/SIMD and its register cost caused the misses it tried to hide.
//  * prevreg eliminated: wpart[1] pre-seeded with (init_inp - db) so the
//    t=0 finish-phase synthesizes prev_out; prev_out = 1 reg 's' + shfl.
//  * everything else identical to R9 (dbuf hs/xs, fast gates, split feat).

#define Bdim 8192
#define Tdim 96
#define Fdim 64
#define Hdim 256
#define BM   32
#define XS   72    // feat row stride (bf16): 64 + 8 pad
#define HS   264   // h row stride (bf16): 256 + 8 pad
#define OS   97    // outbuf row stride (floats)

typedef __attribute__((ext_vector_type(8))) short s16x8;
typedef __attribute__((ext_vector_type(4))) float f32x4;

#define MFMA __builtin_amdgcn_mfma_f32_16x16x32_bf16

__device__ __forceinline__ unsigned short f2bf(float f) {
    union { float f; unsigned u; } v; v.f = f;
    unsigned r = v.u + 0x7FFFu + ((v.u >> 16) & 1u);   // RNE
    return (unsigned short)(r >> 16);
}

__device__ __forceinline__ float sigm_fast(float x) {
    return __builtin_amdgcn_rcpf(1.0f + __expf(-x));
}
__device__ __forceinline__ float tanh_fast(float x) {
    return 1.0f - 2.0f * __builtin_amdgcn_rcpf(1.0f + __expf(2.0f * x));
}

// ---- one-time weight conversion + B-fragment swizzle (unchanged) ----
// frag f = ((w*10 + kt)*3 + g)*2 + n2, lane l: 8 bf16 at sW[f*512 + l*8].
// lane holds B[k][n], k = kt*32 + (l>>4)*8 + j, n = g*256 + w*32 + n2*16 + (l&15).
// kt 0..7: B row k = Wr[k]; kt 8..9: B row = Wk[1 + (kt-8)*32 + (l>>4)*8 + j].
__global__ void prep_swz(const float* __restrict__ Wk, const float* __restrict__ Wr,
                         unsigned short* __restrict__ sW) {
    int idx = blockIdx.x * blockDim.x + threadIdx.x;
    if (idx >= 480 * 64) return;
    int lane = idx & 63, f = idx >> 6;
    int n2 = f & 1;
    int g  = (f >> 1) % 3;
    int kt = (f / 6) % 10;
    int w  = f / 60;
    int q = lane >> 4, cc = lane & 15;
    int n = g * 256 + w * 32 + n2 * 16 + cc;
    unsigned short* d = sW + (size_t)idx * 8;
#pragma unroll
    for (int j = 0; j < 8; ++j) {
        float v;
        if (kt < 8) v = Wr[(size_t)(kt * 32 + q * 8 + j) * 768 + n];
        else        v = Wk[(size_t)(1 + (kt - 8) * 32 + q * 8 + j) * 768 + n];
        d[j] = f2bf(v);
    }
}

__launch_bounds__(1024)
__global__ void gru_mfma11(
    const float* __restrict__ feat,       // [B,T,F]
    const float* __restrict__ init_state, // [B,H]
    const float* __restrict__ init_inp,   // [B,1]
    const unsigned short* __restrict__ sW,
    const float* __restrict__ Wk,         // row 0 (prev_out rank-1 term)
    const float* __restrict__ ib, const float* __restrict__ rb,
    const float* __restrict__ dw, const float* __restrict__ db,
    float* __restrict__ out)              // [B,T,1]
{
    __shared__ __align__(16) unsigned short xs[2][BM * XS];  // feat, dbuf by t&1
    __shared__ __align__(16) unsigned short hs[2][BM * HS];  // h, dbuf by t&1
    __shared__ float wpart[2][16][BM];                       // dbuf by t&1
    __shared__ float outbuf[BM * OS];

    const int tid  = threadIdx.x;
    const int lane = tid & 63;
    const int wv   = tid >> 6;     // wave 0..15: 16 cols per gate
    const int q    = lane >> 4;
    const int c    = lane & 15;
    const int b0   = blockIdx.x * BM;
    const int col  = wv * 16 + c;  // column within each gate, 0..255

    // per-lane epilogue constants (n2 folded into wv)
    const float bz   = ib[col]       + rb[col];
    const float brr  = ib[256 + col] + rb[256 + col];
    const float bxh  = ib[512 + col];
    const float bhh  = rb[512 + col];
    const float wk0z = Wk[col];
    const float wk0r = Wk[256 + col];
    const float wk0h = Wk[512 + col];
    const float dwv  = dw[col];
    const float dbv  = db[0];

    // init h: fp32 in regs + bf16 in LDS (buffer 0)
    float hreg[2][4];     // [mt][i], single column per lane
#pragma unroll
    for (int mt = 0; mt < 2; ++mt)
#pragma unroll
        for (int i = 0; i < 4; ++i) {
            int row = mt * 16 + q * 4 + i;
            float v = init_state[(size_t)(b0 + row) * Hdim + col];
            hreg[mt][i] = v;
            hs[0][row * HS + col] = f2bf(v);
        }

    // seed wpart[1] so the t=0 finish-phase synthesizes prev_out=init_inp:
    // s = dbv + sum_ww wpart[1][ww][r]  ==  init_inp[b0+r]
    if (tid < 16 * BM) {
        int ww = tid >> 5, r = tid & 31;
        wpart[1][ww][r] = (ww == 0) ? (init_inp[b0 + r] - dbv) : 0.0f;
    }

    // stage feat t=0 (1024 threads: 32 rows x 32 float2)
    {
        int r = tid >> 5, fi = tid & 31;
        float2 f = *(const float2*)&feat[((size_t)(b0 + r) * Tdim + 0) * Fdim + fi * 2];
        ushort2 p; p.x = f2bf(f.x); p.y = f2bf(f.y);
        *(ushort2*)&xs[0][r * XS + fi * 2] = p;
    }

    // frag addr: f = w*60 + (kt*3+g)*2 + n2, elements f*512 + lane*8
    const unsigned short* wp0 =
        sW + ((size_t)(wv >> 1) * 60 + (wv & 1)) * 512 + lane * 8;

    __syncthreads();

    for (int t = 0; t < Tdim; ++t) {
        const unsigned short* hsp = hs[t & 1];
        const unsigned short* xsp = xs[t & 1];

        f32x4 az[2], ar[2], ax[2], ah[2];   // [mt]
#pragma unroll
        for (int mt = 0; mt < 2; ++mt) {
            az[mt] = (f32x4)0.0f; ar[mt] = (f32x4)0.0f;
            ax[mt] = (f32x4)0.0f; ah[mt] = (f32x4)0.0f;
        }

        // ---- unified K-loop, single-buffered weight fragments ----
#pragma unroll
        for (int kt = 0; kt < 10; ++kt) {
            s16x8 b0f = *(const s16x8*)(wp0 + (size_t)(kt * 3 + 0) * 1024);
            s16x8 b1f = *(const s16x8*)(wp0 + (size_t)(kt * 3 + 1) * 1024);
            s16x8 b2f = *(const s16x8*)(wp0 + (size_t)(kt * 3 + 2) * 1024);
            s16x8 a0, a1;
            if (kt < 8) {
                a0 = *(const s16x8*)&hsp[c * HS + kt * 32 + q * 8];
                a1 = *(const s16x8*)&hsp[(16 + c) * HS + kt * 32 + q * 8];
            } else {
                a0 = *(const s16x8*)&xsp[c * XS + (kt - 8) * 32 + q * 8];
                a1 = *(const s16x8*)&xsp[(16 + c) * XS + (kt - 8) * 32 + q * 8];
            }
            az[0] = MFMA(a0, b0f, az[0], 0, 0, 0);
            az[1] = MFMA(a1, b0f, az[1], 0, 0, 0);
            ar[0] = MFMA(a0, b1f, ar[0], 0, 0, 0);
            ar[1] = MFMA(a1, b1f, ar[1], 0, 0, 0);
            if (kt < 8) {   // hh terms
                ah[0] = MFMA(a0, b2f, ah[0], 0, 0, 0);
                ah[1] = MFMA(a1, b2f, ah[1], 0, 0, 0);
            } else {        // xh terms
                ax[0] = MFMA(a0, b2f, ax[0], 0, 0, 0);
                ax[1] = MFMA(a1, b2f, ax[1], 0, 0, 0);
            }
        }

        // split feat stage: issue the global load now, ds_write after epilogue
        float2 fnext;
        int fr = tid >> 5, ffi = tid & 31;
        if (t + 1 < Tdim)
            fnext = *(const float2*)&feat[((size_t)(b0 + fr) * Tdim + (t + 1)) * Fdim + ffi * 2];

        __syncthreads();   // S: all hs/xs reads done; wpart(t-1) complete

        // ---- finish step t-1's dense output; prev_out in 's' ----
        float s;
        {
            int r = lane & 31;
            s = dbv;
            const float (*wp)[BM] = wpart[(t - 1) & 1];
#pragma unroll
            for (int ww = 0; ww < 16; ++ww) s += wp[ww][r];
            if (t > 0 && wv == 0 && lane < 32) outbuf[r * OS + (t - 1)] = s;
        }

        // ---- epilogue: gates, h update, fused dense partial reduce ----
        unsigned short* hsn = hs[(t + 1) & 1];
#pragma unroll
        for (int mt = 0; mt < 2; ++mt)
#pragma unroll
            for (int i = 0; i < 4; ++i) {
                float pv = __shfl(s, mt * 16 + q * 4 + i, 64);
                float zz = sigm_fast(az[mt][i] + bz + pv * wk0z);
                float rr = sigm_fast(ar[mt][i] + brr + pv * wk0r);
                float cd = tanh_fast(ax[mt][i] + bxh + pv * wk0h +
                                     rr * (ah[mt][i] + bhh));
                float hn = zz * hreg[mt][i] + (1.0f - zz) * cd;
                hreg[mt][i] = hn;
                hsn[(mt * 16 + q * 4 + i) * HS + col] = f2bf(hn);
                float sp = hn * dwv;
                sp += __shfl_xor(sp, 1, 64);
                sp += __shfl_xor(sp, 2, 64);
                sp += __shfl_xor(sp, 4, 64);
                sp += __shfl_xor(sp, 8, 64);
                if (c == 0) wpart[t & 1][wv][mt * 16 + q * 4 + i] = sp;
            }

        // late half of the feat stage
        if (t + 1 < Tdim) {
            ushort2 p; p.x = f2bf(fnext.x); p.y = f2bf(fnext.y);
            *(ushort2*)&xs[(t + 1) & 1][fr * XS + ffi * 2] = p;
        }
        __syncthreads();   // hs/wpart/xs writes visible for next step
    }

    // final dense output for t=95
    {
        int r = lane & 31;
        float s = dbv;
        const float (*wp)[BM] = wpart[(Tdim - 1) & 1];
#pragma unroll
        for (int ww = 0; ww < 16; ++ww) s += wp[ww][r];
        if (wv == 0 && lane < 32) outbuf[r * OS + (Tdim - 1)] = s;
    }
    __syncthreads();

    // coalesced dump: out[(b0+r)*96 + tt]
    for (int i = tid; i < BM * Tdim; i += 1024) {
        int r = i / Tdim, tt = i - r * Tdim;
        out[(size_t)b0 * Tdim + i] = outbuf[r * OS + tt];
    }
}

extern "C" void kernel_launch(void* const* d_in, const int* in_sizes, int n_in,
                              void* d_out, int out_size, void* d_ws, size_t ws_size,
                              hipStream_t stream) {
    const float* feat       = (const float*)d_in[0];
    const float* init_state = (const float*)d_in[1];
    const float* init_inp   = (const float*)d_in[2];
    const float* Wk         = (const float*)d_in[3];
    const float* Wr         = (const float*)d_in[4];
    const float* ib         = (const float*)d_in[5];
    const float* rb         = (const float*)d_in[6];
    const float* dw         = (const float*)d_in[7];
    const float* db         = (const float*)d_in[8];
    float* out              = (float*)d_out;

    unsigned short* sW = (unsigned short*)d_ws;   // 480 frags * 1 KB = 480 KB

    prep_swz<<<120, 256, 0, stream>>>(Wk, Wr, sW);
    gru_mfma11<<<Bdim / BM, 1024, 0, stream>>>(
        feat, init_state, init_inp, sW, Wk, ib, rb, dw, db, out);
}

// Round 5
// 1722.522 us; speedup vs baseline: 1.0630x; 1.0630x over previous
//
#include <hip/hip_runtime.h>

// GRU decoder, bf16 MFMA. R12: cut the global weight stream, deepen cover.
// R11 post-mortem: removing register pressure changed NOTHING (VGPR=64,
// WRITE 148MB, FETCH 4.24GB identical) and losing the prefetch cost 12%
// (1679 vs R8's 1503). => latency-bound on the 480 KB/block-step
// time-invariant weight stream (30 wave-loads/wave/step, all L1 misses),
// not spill-bound. Changes:
//  * kt=8,9 (feat-weight) tiles staged in LDS ONCE per block (96 KB,
//    time-invariant) -> global weight loads 30->24 per wave per step and
//    two all-LDS K-iterations open the loop as latency cover.
//  * distance-2 global prefetch at 24 frag regs: pre-issue kt0,kt1 into
//    bf[2][3]; at kt, issue kt+2 into the just-consumed slot (R8's depth
//    without R8's 72-reg buffer).
//  * outbuf dropped (direct per-step out write, 128 B/block-step) to fund
//    LDS: total 142 KB <= 160 KB, still 1 block/CU.
// Epilogue/finish structure from R11 (prevreg-free, fast gates).

#define Bdim 8192
#define Tdim 96
#define Fdim 64
#define Hdim 256
#define BM   32
#define XS   72    // feat row stride (bf16): 64 + 8 pad
#define HS   264   // h row stride (bf16): 256 + 8 pad

typedef __attribute__((ext_vector_type(8))) short s16x8;
typedef __attribute__((ext_vector_type(4))) float f32x4;

#define MFMA __builtin_amdgcn_mfma_f32_16x16x32_bf16

__device__ __forceinline__ unsigned short f2bf(float f) {
    union { float f; unsigned u; } v; v.f = f;
    unsigned r = v.u + 0x7FFFu + ((v.u >> 16) & 1u);   // RNE
    return (unsigned short)(r >> 16);
}

__device__ __forceinline__ float sigm_fast(float x) {
    return __builtin_amdgcn_rcpf(1.0f + __expf(-x));
}
__device__ __forceinline__ float tanh_fast(float x) {
    return 1.0f - 2.0f * __builtin_amdgcn_rcpf(1.0f + __expf(2.0f * x));
}

// ---- one-time weight conversion + B-fragment swizzle (unchanged) ----
// frag f = ((w*10 + kt)*3 + g)*2 + n2, lane l: 8 bf16 at sW[f*512 + l*8].
// lane holds B[k][n], k = kt*32 + (l>>4)*8 + j, n = g*256 + w*32 + n2*16 + (l&15).
// kt 0..7: B row k = Wr[k]; kt 8..9: B row = Wk[1 + (kt-8)*32 + (l>>4)*8 + j].
__global__ void prep_swz(const float* __restrict__ Wk, const float* __restrict__ Wr,
                         unsigned short* __restrict__ sW) {
    int idx = blockIdx.x * blockDim.x + threadIdx.x;
    if (idx >= 480 * 64) return;
    int lane = idx & 63, f = idx >> 6;
    int n2 = f & 1;
    int g  = (f >> 1) % 3;
    int kt = (f / 6) % 10;
    int w  = f / 60;
    int q = lane >> 4, cc = lane & 15;
    int n = g * 256 + w * 32 + n2 * 16 + cc;
    unsigned short* d = sW + (size_t)idx * 8;
#pragma unroll
    for (int j = 0; j < 8; ++j) {
        float v;
        if (kt < 8) v = Wr[(size_t)(kt * 32 + q * 8 + j) * 768 + n];
        else        v = Wk[(size_t)(1 + (kt - 8) * 32 + q * 8 + j) * 768 + n];
        d[j] = f2bf(v);
    }
}

__launch_bounds__(1024)
__global__ void gru_mfma12(
    const float* __restrict__ feat,       // [B,T,F]
    const float* __restrict__ init_state, // [B,H]
    const float* __restrict__ init_inp,   // [B,1]
    const unsigned short* __restrict__ sW,
    const float* __restrict__ Wk,         // row 0 (prev_out rank-1 term)
    const float* __restrict__ ib, const float* __restrict__ rb,
    const float* __restrict__ dw, const float* __restrict__ db,
    float* __restrict__ out)              // [B,T,1]
{
    __shared__ __align__(16) unsigned short xs[2][BM * XS];      // 9.2 KB
    __shared__ __align__(16) unsigned short hs[2][BM * HS];      // 33.8 KB
    __shared__ __align__(16) unsigned short wlds[16 * 2 * 3 * 512]; // 96 KB
    __shared__ float wpart[2][16][BM];                           // 4 KB

    const int tid  = threadIdx.x;
    const int lane = tid & 63;
    const int wv   = tid >> 6;     // wave 0..15: 16 cols per gate
    const int q    = lane >> 4;
    const int c    = lane & 15;
    const int b0   = blockIdx.x * BM;
    const int col  = wv * 16 + c;  // column within each gate, 0..255

    // per-lane epilogue constants (n2 folded into wv)
    const float bz   = ib[col]       + rb[col];
    const float brr  = ib[256 + col] + rb[256 + col];
    const float bxh  = ib[512 + col];
    const float bhh  = rb[512 + col];
    const float wk0z = Wk[col];
    const float wk0r = Wk[256 + col];
    const float wk0h = Wk[512 + col];
    const float dwv  = dw[col];
    const float dbv  = db[0];

    // init h: fp32 in regs + bf16 in LDS (buffer 0)
    float hreg[2][4];     // [mt][i], single column per lane
#pragma unroll
    for (int mt = 0; mt < 2; ++mt)
#pragma unroll
        for (int i = 0; i < 4; ++i) {
            int row = mt * 16 + q * 4 + i;
            float v = init_state[(size_t)(b0 + row) * Hdim + col];
            hreg[mt][i] = v;
            hs[0][row * HS + col] = f2bf(v);
        }

    // seed wpart[1] so the t=0 finish-phase synthesizes prev_out=init_inp:
    // s = dbv + sum_ww wpart[1][ww][r]  ==  init_inp[b0+r]
    if (tid < 16 * BM) {
        int ww = tid >> 5, r = tid & 31;
        wpart[1][ww][r] = (ww == 0) ? (init_inp[b0 + r] - dbv) : 0.0f;
    }

    // stage feat t=0 (1024 threads: 32 rows x 32 float2)
    {
        int r = tid >> 5, fi = tid & 31;
        float2 f = *(const float2*)&feat[((size_t)(b0 + r) * Tdim + 0) * Fdim + fi * 2];
        ushort2 p; p.x = f2bf(f.x); p.y = f2bf(f.y);
        *(ushort2*)&xs[0][r * XS + fi * 2] = p;
    }

    // frag addr: f = w*60 + (kt*3+g)*2 + n2, elements f*512 + lane*8
    const unsigned short* wp0 =
        sW + ((size_t)(wv >> 1) * 60 + (wv & 1)) * 512 + lane * 8;

    // ---- one-time LDS stage of the kt=8,9 (feat-weight) tiles: 96 KB ----
    // wave wv's 6 frags at wlds[wv*3072 + (j*3+g)*512 + lane*8]
    {
        unsigned short* wld = wlds + (size_t)wv * 3072 + lane * 8;
#pragma unroll
        for (int j = 0; j < 2; ++j)
#pragma unroll
            for (int g = 0; g < 3; ++g)
                *(s16x8*)(wld + (j * 3 + g) * 512) =
                    *(const s16x8*)(wp0 + (size_t)((8 + j) * 3 + g) * 1024);
    }

    __syncthreads();

    const unsigned short* wld = wlds + (size_t)wv * 3072 + lane * 8;

    for (int t = 0; t < Tdim; ++t) {
        const unsigned short* hsp = hs[t & 1];
        const unsigned short* xsp = xs[t & 1];

        f32x4 az[2], ar[2], ax[2], ah[2];   // [mt]
#pragma unroll
        for (int mt = 0; mt < 2; ++mt) {
            az[mt] = (f32x4)0.0f; ar[mt] = (f32x4)0.0f;
            ax[mt] = (f32x4)0.0f; ah[mt] = (f32x4)0.0f;
        }

        // pre-issue global frags for kt=0,1 (distance-2 pipeline head)
        s16x8 bf[2][3];
#pragma unroll
        for (int g = 0; g < 3; ++g)
            bf[0][g] = *(const s16x8*)(wp0 + (size_t)(0 * 3 + g) * 1024);
#pragma unroll
        for (int g = 0; g < 3; ++g)
            bf[1][g] = *(const s16x8*)(wp0 + (size_t)(1 * 3 + g) * 1024);

        // ---- staged iterations first (b from LDS, a from xs): latency cover ----
#pragma unroll
        for (int j = 0; j < 2; ++j) {
            s16x8 w0 = *(const s16x8*)(wld + (j * 3 + 0) * 512);
            s16x8 w1 = *(const s16x8*)(wld + (j * 3 + 1) * 512);
            s16x8 w2 = *(const s16x8*)(wld + (j * 3 + 2) * 512);
            s16x8 a0 = *(const s16x8*)&xsp[c * XS + j * 32 + q * 8];
            s16x8 a1 = *(const s16x8*)&xsp[(16 + c) * XS + j * 32 + q * 8];
            az[0] = MFMA(a0, w0, az[0], 0, 0, 0);
            az[1] = MFMA(a1, w0, az[1], 0, 0, 0);
            ar[0] = MFMA(a0, w1, ar[0], 0, 0, 0);
            ar[1] = MFMA(a1, w1, ar[1], 0, 0, 0);
            ax[0] = MFMA(a0, w2, ax[0], 0, 0, 0);
            ax[1] = MFMA(a1, w2, ax[1], 0, 0, 0);
        }

        // ---- global-streamed iterations kt=0..7 (b prefetched, a from hs) ----
#pragma unroll
        for (int kt = 0; kt < 8; ++kt) {
            s16x8 w0 = bf[kt & 1][0];
            s16x8 w1 = bf[kt & 1][1];
            s16x8 w2 = bf[kt & 1][2];
            if (kt + 2 < 8) {
#pragma unroll
                for (int g = 0; g < 3; ++g)
                    bf[kt & 1][g] =
                        *(const s16x8*)(wp0 + (size_t)((kt + 2) * 3 + g) * 1024);
            }
            s16x8 a0 = *(const s16x8*)&hsp[c * HS + kt * 32 + q * 8];
            s16x8 a1 = *(const s16x8*)&hsp[(16 + c) * HS + kt * 32 + q * 8];
            az[0] = MFMA(a0, w0, az[0], 0, 0, 0);
            az[1] = MFMA(a1, w0, az[1], 0, 0, 0);
            ar[0] = MFMA(a0, w1, ar[0], 0, 0, 0);
            ar[1] = MFMA(a1, w1, ar[1], 0, 0, 0);
            ah[0] = MFMA(a0, w2, ah[0], 0, 0, 0);
            ah[1] = MFMA(a1, w2, ah[1], 0, 0, 0);
        }

        // split feat stage: issue the global load now, ds_write after epilogue
        float2 fnext;
        int fr = tid >> 5, ffi = tid & 31;
        if (t + 1 < Tdim)
            fnext = *(const float2*)&feat[((size_t)(b0 + fr) * Tdim + (t + 1)) * Fdim + ffi * 2];

        __syncthreads();   // S: all hs/xs reads done; wpart(t-1) complete

        // ---- finish step t-1's dense output; prev_out in 's' ----
        float s;
        {
            int r = lane & 31;
            s = dbv;
            const float (*wp)[BM] = wpart[(t - 1) & 1];
#pragma unroll
            for (int ww = 0; ww < 16; ++ww) s += wp[ww][r];
            if (t > 0 && wv == 0 && lane < 32)
                out[(size_t)(b0 + r) * Tdim + (t - 1)] = s;
        }

        // ---- epilogue: gates, h update, fused dense partial reduce ----
        unsigned short* hsn = hs[(t + 1) & 1];
#pragma unroll
        for (int mt = 0; mt < 2; ++mt)
#pragma unroll
            for (int i = 0; i < 4; ++i) {
                float pv = __shfl(s, mt * 16 + q * 4 + i, 64);
                float zz = sigm_fast(az[mt][i] + bz + pv * wk0z);
                float rr = sigm_fast(ar[mt][i] + brr + pv * wk0r);
                float cd = tanh_fast(ax[mt][i] + bxh + pv * wk0h +
                                     rr * (ah[mt][i] + bhh));
                float hn = zz * hreg[mt][i] + (1.0f - zz) * cd;
                hreg[mt][i] = hn;
                hsn[(mt * 16 + q * 4 + i) * HS + col] = f2bf(hn);
                float sp = hn * dwv;
                sp += __shfl_xor(sp, 1, 64);
                sp += __shfl_xor(sp, 2, 64);
                sp += __shfl_xor(sp, 4, 64);
                sp += __shfl_xor(sp, 8, 64);
                if (c == 0) wpart[t & 1][wv][mt * 16 + q * 4 + i] = sp;
            }

        // late half of the feat stage
        if (t + 1 < Tdim) {
            ushort2 p; p.x = f2bf(fnext.x); p.y = f2bf(fnext.y);
            *(ushort2*)&xs[(t + 1) & 1][fr * XS + ffi * 2] = p;
        }
        __syncthreads();   // hs/wpart/xs writes visible for next step
    }

    // final dense output for t=95
    {
        int r = lane & 31;
        float s = dbv;
        const float (*wp)[BM] = wpart[(Tdim - 1) & 1];
#pragma unroll
        for (int ww = 0; ww < 16; ++ww) s += wp[ww][r];
        if (wv == 0 && lane < 32)
            out[(size_t)(b0 + r) * Tdim + (Tdim - 1)] = s;
    }
}

extern "C" void kernel_launch(void* const* d_in, const int* in_sizes, int n_in,
                              void* d_out, int out_size, void* d_ws, size_t ws_size,
                              hipStream_t stream) {
    const float* feat       = (const float*)d_in[0];
    const float* init_state = (const float*)d_in[1];
    const float* init_inp   = (const float*)d_in[2];
    const float* Wk         = (const float*)d_in[3];
    const float* Wr         = (const float*)d_in[4];
    const float* ib         = (const float*)d_in[5];
    const float* rb         = (const float*)d_in[6];
    const float* dw         = (const float*)d_in[7];
    const float* db         = (const float*)d_in[8];
    float* out              = (float*)d_out;

    unsigned short* sW = (unsigned short*)d_ws;   // 480 frags * 1 KB = 480 KB

    prep_swz<<<120, 256, 0, stream>>>(Wk, Wr, sW);
    gru_mfma12<<<Bdim / BM, 1024, 0, stream>>>(
        feat, init_state, init_inp, sW, Wk, ib, rb, dw, db, out);
}